// Round 19
// baseline (102.253 us; speedup 1.0000x reference)
//
#include <hip/hip_runtime.h>

#define CHVOL (128*128*128)

typedef float f32x4 __attribute__((ext_vector_type(4)));

// Streaming load: nt flag bypasses L1 (no MSHR allocation). Image lines are
// touched exactly once -> L1 gives zero reuse; R16 diagnosis: k_main runs at
// 1/6 of achievable HBM BW with abundant loads in flight => per-CU L1 miss
// queue is the throttle candidate.
__device__ __forceinline__ f32x4 ldnt(const float* p) {
    return __builtin_nontemporal_load((const f32x4*)p);
}

// L0 stats (9): [S_-2, S_-1, S_0, S_1, S_2, S_3, S_4, S_5, T=sum x*ln x]
__device__ __forceinline__ void accum9(float* a, float x) {
    bool nz = (x != 0.0f);
    float u = nz ? __builtin_amdgcn_rcpf(x) : 0.0f;
    float l = nz ? __logf(x) : 0.0f;
    float x2 = x * x;
    float x4 = x2 * x2;
    a[0] = fmaf(u, u, a[0]);
    a[1] += u;
    a[2] += nz ? 1.0f : 0.0f;
    a[3] += x;
    a[4] += x2;
    a[5] = fmaf(x2, x, a[5]);
    a[6] += x4;
    a[7] = fmaf(x4, x, a[7]);
    a[8] = fmaf(x, l, a[8]);
}

// Pooled-level stats (8): [S_-2, S_-1, S_0, S_2, S_3, S_4, S_5, T].
// S_1 dropped: pooling preserves the total sum (k_fin substitutes b).
__device__ __forceinline__ void accum8(float* a, float x) {
    bool nz = (x != 0.0f);
    float u = nz ? __builtin_amdgcn_rcpf(x) : 0.0f;
    float l = nz ? __logf(x) : 0.0f;
    float x2 = x * x;
    float x4 = x2 * x2;
    a[0] = fmaf(u, u, a[0]);
    a[1] += u;
    a[2] += nz ? 1.0f : 0.0f;
    a[3] += x2;
    a[4] = fmaf(x2, x, a[4]);
    a[5] += x4;
    a[6] = fmaf(x4, x, a[6]);
    a[7] = fmaf(x, l, a[7]);
}

// DPP wave-64 sum (rocPRIM idiom): 6 VALU adds, zero LDS-pipe traffic.
template<int CTRL, int RMASK>
__device__ __forceinline__ float dppadd(float x) {
    int y = __builtin_amdgcn_update_dpp(0, __float_as_int(x), CTRL, RMASK, 0xf, true);
    return x + __int_as_float(y);
}
__device__ __forceinline__ float wave_sum_dpp(float v) {
    v = dppadd<0x111, 0xf>(v);   // row_shr:1
    v = dppadd<0x112, 0xf>(v);   // row_shr:2
    v = dppadd<0x114, 0xf>(v);   // row_shr:4
    v = dppadd<0x118, 0xf>(v);   // row_shr:8
    v = dppadd<0x142, 0xa>(v);   // row_bcast:15
    v = dppadd<0x143, 0xc>(v);   // row_bcast:31 -> lane 63 = total
    return v;
}

template<int NS>
__device__ __forceinline__ void block_reduce(float* acc, float* red, int t) {
    #pragma unroll
    for (int s = 0; s < NS; ++s) {
        float v = wave_sum_dpp(acc[s]);
        if ((t & 63) == 63) red[(t >> 6) * NS + s] = v;
    }
    __syncthreads();
}

// ===== PRODUCER: R16 body + nontemporal image loads (only change) =====
// Region = 128(x) x 8(y) x 8(z). Thread (x5,yp,zq) owns a 4x*2y*4z brick.
__global__ __launch_bounds__(256) void k_main(const float* __restrict__ img,
                                              float* __restrict__ part,
                                              float* __restrict__ l3map) {
    __shared__ float zm[256];        // [yp 4][zq 2][x5 32]
    __shared__ float red[33 * 4];

    const int t  = threadIdx.x;
    const int r  = blockIdx.x;        // 0..255
    const int ch = blockIdx.y;        // 0..5
    const int ry = r & 15, rz = r >> 4;

    const int x5 = t & 31;            // x = 4*x5 .. 4*x5+3
    const int yp = (t >> 5) & 3;      // y = 2*yp, 2*yp+1
    const int zq = t >> 7;            // z = 4*zq .. 4*zq+3

    const float* tb = img + (size_t)ch * CHVOL + rz * (8 * 16384) + ry * (8 * 128)
                    + (zq * 4) * 16384 + (yp * 2) * 128 + x5 * 4;

    float acc[33];
    #pragma unroll
    for (int j = 0; j < 33; ++j) acc[j] = 0.0f;

    float brick = 0.0f;
    #pragma unroll
    for (int h = 0; h < 2; ++h) {     // batch h: dz = 2h, 2h+1
        f32x4 v[4];
        #pragma unroll
        for (int dz = 0; dz < 2; ++dz)
            #pragma unroll
            for (int dy = 0; dy < 2; ++dy)
                v[dz * 2 + dy] = ldnt(tb + (2 * h + dz) * 16384 + dy * 128);

        // L0 (order identical to R14/R16: i ascending).
        #pragma unroll
        for (int i = 0; i < 4; ++i) {
            accum9(acc, v[i].x); accum9(acc, v[i].y); accum9(acc, v[i].z); accum9(acc, v[i].w);
        }
        // L1: same trees as R14/R16.
        float ax0 = v[0].x + v[0].y, ax1 = v[1].x + v[1].y;
        float ax2 = v[2].x + v[2].y, ax3 = v[3].x + v[3].y;
        float bx0 = v[0].z + v[0].w, bx1 = v[1].z + v[1].w;
        float bx2 = v[2].z + v[2].w, bx3 = v[3].z + v[3].w;
        float A = (ax0 + ax1) + (ax2 + ax3);
        float B = (bx0 + bx1) + (bx2 + bx3);
        accum8(acc + 9, A); accum8(acc + 9, B);
        brick += A + B;
    }

    zm[yp * 64 + zq * 32 + x5] = brick;
    __syncthreads();

    // L2: 32(x) x 2(y'') x 2(z'')
    if (t < 128) {
        int x = t & 31, zpp = (t >> 5) & 1, ypp = t >> 6;
        float s = zm[(2 * ypp) * 64 + zpp * 32 + x] + zm[(2 * ypp + 1) * 64 + zpp * 32 + x];
        accum8(acc + 17, s);
    }
    // L3: 16 cells
    if (t < 16) {
        float s = 0.0f;
        #pragma unroll
        for (int q = 0; q < 8; ++q)
            s += zm[q * 32 + 2 * t] + zm[q * 32 + 2 * t + 1];
        accum8(acc + 25, s);
        l3map[(size_t)ch * 4096 + rz * 256 + ry * 16 + t] = s;
    }

    block_reduce<33>(acc, red, t);
    if (t < 33)
        part[((size_t)ch * 33 + t) * 256 + r] =
            red[t] + red[33 + t] + red[66 + t] + red[99 + t];
}

// ===== CONSUMER: unchanged from R15/R16 =====
// sst layout: [0..8]=L0(9), [9..16]=L1, [17..24]=L2, [25..32]=L3,
//             [33..40]=L4, [41..48]=L5.
__global__ __launch_bounds__(512) void k_fin(const float* __restrict__ part,
                                             const float* __restrict__ l3map,
                                             const int* __restrict__ bounds,
                                             float* __restrict__ out) {
    __shared__ float M4[512];
    __shared__ float redA[33 * 4];
    __shared__ float redB[8 * 4];
    __shared__ float sst[49];

    const int t  = threadIdx.x;
    const int ch = blockIdx.x;

    if (t < 256) {
        float acc[33];
        #pragma unroll
        for (int j = 0; j < 33; ++j)
            acc[j] = part[((size_t)ch * 33 + j) * 256 + t];
        #pragma unroll
        for (int s = 0; s < 33; ++s) {
            float v = wave_sum_dpp(acc[s]);
            if ((t & 63) == 63) redA[(t >> 6) * 33 + s] = v;
        }
    } else {
        const float2* L3 = (const float2*)(l3map + (size_t)ch * 4096);
        const int th = t - 256;
        float a8[8];
        #pragma unroll
        for (int j = 0; j < 8; ++j) a8[j] = 0.0f;
        #pragma unroll
        for (int i = 0; i < 2; ++i) {
            int c = th + i * 256;
            int x = c & 7, y = (c >> 3) & 7, z = c >> 6;
            const float2* p = L3 + z * 256 + y * 16 + x;   // f2 idx = 2z*128+2y*8+x
            float2 b0 = p[0], b1 = p[8], b2 = p[128], b3 = p[136];
            float s = (b0.x + b0.y) + (b1.x + b1.y) + (b2.x + b2.y) + (b3.x + b3.y);
            M4[c] = s;
            accum8(a8, s);
        }
        #pragma unroll
        for (int s = 0; s < 8; ++s) {
            float v = wave_sum_dpp(a8[s]);
            if ((t & 63) == 63) redB[((t >> 6) - 4) * 8 + s] = v;
        }
    }
    __syncthreads();

    if (t < 33) sst[t] = redA[t] + redA[33 + t] + redA[66 + t] + redA[99 + t];
    if (t >= 33 && t < 41) {
        int s = t - 33;
        sst[33 + s] = redB[s] + redB[8 + s] + redB[16 + s] + redB[24 + s];
    }
    if (t < 64) {
        float c8[8];
        #pragma unroll
        for (int j = 0; j < 8; ++j) c8[j] = 0.0f;
        int x = t & 3, y = (t >> 2) & 3, z = t >> 4;
        const float2* p = (const float2*)M4 + z * 64 + y * 8 + x;  // 2z*32+2y*4+x
        float2 b0 = p[0], b1 = p[4], b2 = p[32], b3 = p[36];
        float s = (b0.x + b0.y) + (b1.x + b1.y) + (b2.x + b2.y) + (b3.x + b3.y);
        accum8(c8, s);
        #pragma unroll
        for (int j = 0; j < 8; ++j) {
            float v = wave_sum_dpp(c8[j]);
            if (t == 63) sst[41 + j] = v;
        }
    }
    __syncthreads();

    // finale: least-squares slope, double precision, 8 outputs
    if (t < 8) {
        int k = bounds[t];
        const double LN2 = 0.6931471805599453094;
        double b  = (double)sst[3];          // S_1 at level 0 == total sum
        double lb = log(b);
        double num = 0.0;
        #pragma unroll
        for (int s = 0; s < 6; ++s) {
            const float* st = (s == 0) ? sst : sst + 9 + 8 * (s - 1);
            double p;
            if (s == 0) {
                if (k == 1) p = ((double)st[8] - lb * (double)st[3]) / b;
                else        p = log((double)st[k + 2]) - (double)k * lb;
            } else {
                // 8-stat layout [S-2,S-1,S0,S2,S3,S4,S5,T]; S_1 == b.
                if (k == 1) p = (double)st[7] / b - lb;
                else {
                    int idx = (k < 1) ? (k + 2) : (k + 1);
                    p = log((double)st[idx]) - (double)k * lb;
                }
            }
            num += (6.0 * s - 15.0) * LN2 * p;   // n*q_s - qs
        }
        double den = 105.0 * LN2 * LN2;          // n*q2s - qs^2
        double aa  = (k == 1) ? 1.0 : 1.0 / (double)(k - 1);
        out[ch * 8 + t] = (float)(aa * num / den);
    }
}

extern "C" void kernel_launch(void* const* d_in, const int* in_sizes, int n_in,
                              void* d_out, int out_size, void* d_ws, size_t ws_size,
                              hipStream_t stream) {
    const float* img    = (const float*)d_in[0];
    const int*   bounds = (const int*)d_in[1];
    float*       out    = (float*)d_out;
    float*       ws     = (float*)d_ws;

    // ws layout (floats): part[6*33*256=50688] @0, l3map[6*4096=24576] @50688.
    float* part  = ws;
    float* l3map = ws + 50688;

    k_main<<<dim3(256, 6), 256, 0, stream>>>(img, part, l3map);
    k_fin<<<6, 512, 0, stream>>>(part, l3map, bounds, out);
}

// Round 20
// 97.696 us; speedup vs baseline: 1.0466x; 1.0466x over previous
//
#include <hip/hip_runtime.h>

#define CHVOL (128*128*128)

// L0 stats (9): [S_-2, S_-1, S_0, S_1, S_2, S_3, S_4, S_5, T=sum x*ln x]
__device__ __forceinline__ void accum9(float* a, float x) {
    bool nz = (x != 0.0f);
    float u = nz ? __builtin_amdgcn_rcpf(x) : 0.0f;
    float l = nz ? __logf(x) : 0.0f;
    float x2 = x * x;
    float x4 = x2 * x2;
    a[0] = fmaf(u, u, a[0]);
    a[1] += u;
    a[2] += nz ? 1.0f : 0.0f;
    a[3] += x;
    a[4] += x2;
    a[5] = fmaf(x2, x, a[5]);
    a[6] += x4;
    a[7] = fmaf(x4, x, a[7]);
    a[8] = fmaf(x, l, a[8]);
}

// Pooled-level stats (8): [S_-2, S_-1, S_0, S_2, S_3, S_4, S_5, T].
// S_1 dropped: pooling preserves the total sum, so S_1(level s) == b exactly
// (k_fin substitutes b). Saves regs + DPP reduces.
__device__ __forceinline__ void accum8(float* a, float x) {
    bool nz = (x != 0.0f);
    float u = nz ? __builtin_amdgcn_rcpf(x) : 0.0f;
    float l = nz ? __logf(x) : 0.0f;
    float x2 = x * x;
    float x4 = x2 * x2;
    a[0] = fmaf(u, u, a[0]);
    a[1] += u;
    a[2] += nz ? 1.0f : 0.0f;
    a[3] += x2;
    a[4] = fmaf(x2, x, a[4]);
    a[5] += x4;
    a[6] = fmaf(x4, x, a[6]);
    a[7] = fmaf(x, l, a[7]);
}

// DPP wave-64 sum (rocPRIM idiom): 6 VALU adds, zero LDS-pipe traffic.
// (R14: replacing shfl block_reduce with this was -17.7 us total — the LDS
// pipe was the hidden serialization floor.)
template<int CTRL, int RMASK>
__device__ __forceinline__ float dppadd(float x) {
    int y = __builtin_amdgcn_update_dpp(0, __float_as_int(x), CTRL, RMASK, 0xf, true);
    return x + __int_as_float(y);
}
__device__ __forceinline__ float wave_sum_dpp(float v) {
    v = dppadd<0x111, 0xf>(v);   // row_shr:1
    v = dppadd<0x112, 0xf>(v);   // row_shr:2
    v = dppadd<0x114, 0xf>(v);   // row_shr:4
    v = dppadd<0x118, 0xf>(v);   // row_shr:8
    v = dppadd<0x142, 0xa>(v);   // row_bcast:15
    v = dppadd<0x143, 0xc>(v);   // row_bcast:31 -> lane 63 = total
    return v;
}

template<int NS>
__device__ __forceinline__ void block_reduce(float* acc, float* red, int t) {
    #pragma unroll
    for (int s = 0; s < NS; ++s) {
        float v = wave_sum_dpp(acc[s]);
        if ((t & 63) == 63) red[(t >> 6) * NS + s] = v;
    }
    __syncthreads();
}

// ===== PRODUCER: in-thread pyramid + DPP + natural register allocation =====
// (R16 config — best verified: total 97.7 us, absmax 0.0. nt-loads (R19)
// regressed −4.6 us and are reverted; forced occupancy caps spill (R15).)
// Region = 128(x) x 8(y) x 8(z). Thread (x5,yp,zq) owns a 4x*2y*4z brick.
__global__ __launch_bounds__(256) void k_main(const float* __restrict__ img,
                                              float* __restrict__ part,
                                              float* __restrict__ l3map) {
    __shared__ float zm[256];        // [yp 4][zq 2][x5 32]
    __shared__ float red[33 * 4];

    const int t  = threadIdx.x;
    const int r  = blockIdx.x;        // 0..255
    const int ch = blockIdx.y;        // 0..5
    const int ry = r & 15, rz = r >> 4;

    const int x5 = t & 31;            // x = 4*x5 .. 4*x5+3
    const int yp = (t >> 5) & 3;      // y = 2*yp, 2*yp+1
    const int zq = t >> 7;            // z = 4*zq .. 4*zq+3

    const float* tb = img + (size_t)ch * CHVOL + rz * (8 * 16384) + ry * (8 * 128)
                    + (zq * 4) * 16384 + (yp * 2) * 128 + x5 * 4;

    float acc[33];
    #pragma unroll
    for (int j = 0; j < 33; ++j) acc[j] = 0.0f;

    float brick = 0.0f;
    #pragma unroll
    for (int h = 0; h < 2; ++h) {     // batch h: dz = 2h, 2h+1
        float4 v[4];
        #pragma unroll
        for (int dz = 0; dz < 2; ++dz)
            #pragma unroll
            for (int dy = 0; dy < 2; ++dy)
                v[dz * 2 + dy] = *(const float4*)(tb + (2 * h + dz) * 16384 + dy * 128);

        // L0 (order identical to R14/R16: i ascending).
        #pragma unroll
        for (int i = 0; i < 4; ++i) {
            accum9(acc, v[i].x); accum9(acc, v[i].y); accum9(acc, v[i].z); accum9(acc, v[i].w);
        }
        // L1: same trees as R14/R16 (in-thread, zero cross-lane ops).
        float ax0 = v[0].x + v[0].y, ax1 = v[1].x + v[1].y;
        float ax2 = v[2].x + v[2].y, ax3 = v[3].x + v[3].y;
        float bx0 = v[0].z + v[0].w, bx1 = v[1].z + v[1].w;
        float bx2 = v[2].z + v[2].w, bx3 = v[3].z + v[3].w;
        float A = (ax0 + ax1) + (ax2 + ax3);
        float B = (bx0 + bx1) + (bx2 + bx3);
        accum8(acc + 9, A); accum8(acc + 9, B);
        brick += A + B;
    }

    zm[yp * 64 + zq * 32 + x5] = brick;
    __syncthreads();

    // L2: 32(x) x 2(y'') x 2(z'')
    if (t < 128) {
        int x = t & 31, zpp = (t >> 5) & 1, ypp = t >> 6;
        float s = zm[(2 * ypp) * 64 + zpp * 32 + x] + zm[(2 * ypp + 1) * 64 + zpp * 32 + x];
        accum8(acc + 17, s);
    }
    // L3: 16 cells
    if (t < 16) {
        float s = 0.0f;
        #pragma unroll
        for (int q = 0; q < 8; ++q)
            s += zm[q * 32 + 2 * t] + zm[q * 32 + 2 * t + 1];
        accum8(acc + 25, s);
        l3map[(size_t)ch * 4096 + rz * 256 + ry * 16 + t] = s;
    }

    block_reduce<33>(acc, red, t);
    if (t < 33)
        part[((size_t)ch * 33 + t) * 256 + r] =
            red[t] + red[33 + t] + red[66 + t] + red[99 + t];
}

// ===== CONSUMER: lean, 33-stat part + 8-stat L4/L5 (R15/R16) =====
// sst layout: [0..8]=L0(9), [9..16]=L1, [17..24]=L2, [25..32]=L3,
//             [33..40]=L4, [41..48]=L5.
__global__ __launch_bounds__(512) void k_fin(const float* __restrict__ part,
                                             const float* __restrict__ l3map,
                                             const int* __restrict__ bounds,
                                             float* __restrict__ out) {
    __shared__ float M4[512];
    __shared__ float redA[33 * 4];
    __shared__ float redB[8 * 4];
    __shared__ float sst[49];

    const int t  = threadIdx.x;
    const int ch = blockIdx.x;

    if (t < 256) {
        float acc[33];
        #pragma unroll
        for (int j = 0; j < 33; ++j)
            acc[j] = part[((size_t)ch * 33 + j) * 256 + t];
        #pragma unroll
        for (int s = 0; s < 33; ++s) {
            float v = wave_sum_dpp(acc[s]);
            if ((t & 63) == 63) redA[(t >> 6) * 33 + s] = v;
        }
    } else {
        const float2* L3 = (const float2*)(l3map + (size_t)ch * 4096);
        const int th = t - 256;
        float a8[8];
        #pragma unroll
        for (int j = 0; j < 8; ++j) a8[j] = 0.0f;
        #pragma unroll
        for (int i = 0; i < 2; ++i) {
            int c = th + i * 256;
            int x = c & 7, y = (c >> 3) & 7, z = c >> 6;
            const float2* p = L3 + z * 256 + y * 16 + x;   // f2 idx = 2z*128+2y*8+x
            float2 b0 = p[0], b1 = p[8], b2 = p[128], b3 = p[136];
            float s = (b0.x + b0.y) + (b1.x + b1.y) + (b2.x + b2.y) + (b3.x + b3.y);
            M4[c] = s;
            accum8(a8, s);
        }
        #pragma unroll
        for (int s = 0; s < 8; ++s) {
            float v = wave_sum_dpp(a8[s]);
            if ((t & 63) == 63) redB[((t >> 6) - 4) * 8 + s] = v;
        }
    }
    __syncthreads();

    if (t < 33) sst[t] = redA[t] + redA[33 + t] + redA[66 + t] + redA[99 + t];
    if (t >= 33 && t < 41) {
        int s = t - 33;
        sst[33 + s] = redB[s] + redB[8 + s] + redB[16 + s] + redB[24 + s];
    }
    if (t < 64) {
        float c8[8];
        #pragma unroll
        for (int j = 0; j < 8; ++j) c8[j] = 0.0f;
        int x = t & 3, y = (t >> 2) & 3, z = t >> 4;
        const float2* p = (const float2*)M4 + z * 64 + y * 8 + x;  // 2z*32+2y*4+x
        float2 b0 = p[0], b1 = p[4], b2 = p[32], b3 = p[36];
        float s = (b0.x + b0.y) + (b1.x + b1.y) + (b2.x + b2.y) + (b3.x + b3.y);
        accum8(c8, s);
        #pragma unroll
        for (int j = 0; j < 8; ++j) {
            float v = wave_sum_dpp(c8[j]);
            if (t == 63) sst[41 + j] = v;
        }
    }
    __syncthreads();

    // finale: least-squares slope, double precision, 8 outputs
    if (t < 8) {
        int k = bounds[t];
        const double LN2 = 0.6931471805599453094;
        double b  = (double)sst[3];          // S_1 at level 0 == total sum
        double lb = log(b);
        double num = 0.0;
        #pragma unroll
        for (int s = 0; s < 6; ++s) {
            const float* st = (s == 0) ? sst : sst + 9 + 8 * (s - 1);
            double p;
            if (s == 0) {
                if (k == 1) p = ((double)st[8] - lb * (double)st[3]) / b;
                else        p = log((double)st[k + 2]) - (double)k * lb;
            } else {
                // 8-stat layout [S-2,S-1,S0,S2,S3,S4,S5,T]; S_1 == b.
                if (k == 1) p = (double)st[7] / b - lb;
                else {
                    int idx = (k < 1) ? (k + 2) : (k + 1);
                    p = log((double)st[idx]) - (double)k * lb;
                }
            }
            num += (6.0 * s - 15.0) * LN2 * p;   // n*q_s - qs
        }
        double den = 105.0 * LN2 * LN2;          // n*q2s - qs^2
        double aa  = (k == 1) ? 1.0 : 1.0 / (double)(k - 1);
        out[ch * 8 + t] = (float)(aa * num / den);
    }
}

extern "C" void kernel_launch(void* const* d_in, const int* in_sizes, int n_in,
                              void* d_out, int out_size, void* d_ws, size_t ws_size,
                              hipStream_t stream) {
    const float* img    = (const float*)d_in[0];
    const int*   bounds = (const int*)d_in[1];
    float*       out    = (float*)d_out;
    float*       ws     = (float*)d_ws;

    // ws layout (floats): part[6*33*256=50688] @0, l3map[6*4096=24576] @50688.
    float* part  = ws;
    float* l3map = ws + 50688;

    k_main<<<dim3(256, 6), 256, 0, stream>>>(img, part, l3map);
    k_fin<<<6, 512, 0, stream>>>(part, l3map, bounds, out);
}